// Round 1
// baseline (26655.237 us; speedup 1.0000x reference)
//
#include <hip/hip_runtime.h>
#include <hip/hip_bf16.h>

#define BB  512
#define TT  256
#define MM  81
#define HEE 256

// ---- workspace layout (float offsets) ----
#define OFF_WAHT   0          // [512][256]  W_ah^T
#define OFF_WENC   131072     // [337][256] float4 (i,f,g,o)  k<81: Wih_e, k>=81: Whh_e
#define OFF_WD1HC  476160     // [512][256]  W_d1[:, :512]^T
#define OFF_WDEC   607232     // [257][256] float4 (i,f,g,o)  k==0: Wih_d, k>=1: Whh_d
#define OFF_ATTN   870400     // [512][81]   attn_in
#define OFF_ENCW   911872     // [512][256]  enc . W_fc[:256]
#define OFF_ENC    1042944    // [512][256][256] input_encoded (fp32)
#define OFF_ENCT   34597376   // [512][256(h)][256(t)] enc_proj transposed, bf16 (16777216 float slots)
#define WS_FLOATS  51374592

__device__ __forceinline__ float frcp(float x) { return __builtin_amdgcn_rcpf(x); }
__device__ __forceinline__ float fsig(float x) { return frcp(1.f + __expf(-x)); }
__device__ __forceinline__ float ftanh(float x) { return 1.f - 2.f * frcp(__expf(2.f * x) + 1.f); }

// ---------------- weight prep (transpose/pack) ----------------
__global__ void k_prep(const float* __restrict__ W_ah, const float* __restrict__ Wih_e,
                       const float* __restrict__ Whh_e, const float* __restrict__ W_d1,
                       const float* __restrict__ Wih_d, const float* __restrict__ Whh_d,
                       float* __restrict__ ws) {
  int idx = blockIdx.x * 256 + threadIdx.x;
  if (idx < 131072) {  // k<512 x j<256
    int k = idx >> 8, j = idx & 255;
    ws[OFF_WAHT + idx]  = W_ah[j * 512 + k];
    ws[OFF_WD1HC + idx] = W_d1[j * 768 + k];
  }
  if (idx < 86272) {   // 337*256 float4
    int k = idx >> 8, j = idx & 255;
    float4 v;
    if (k < 81) {
      v.x = Wih_e[(0 * 256 + j) * 81 + k];
      v.y = Wih_e[(1 * 256 + j) * 81 + k];
      v.z = Wih_e[(2 * 256 + j) * 81 + k];
      v.w = Wih_e[(3 * 256 + j) * 81 + k];
    } else {
      int kk = k - 81;
      v.x = Whh_e[(0 * 256 + j) * 256 + kk];
      v.y = Whh_e[(1 * 256 + j) * 256 + kk];
      v.z = Whh_e[(2 * 256 + j) * 256 + kk];
      v.w = Whh_e[(3 * 256 + j) * 256 + kk];
    }
    reinterpret_cast<float4*>(ws + OFF_WENC)[idx] = v;
  }
  if (idx < 65792) {   // 257*256 float4
    int k = idx >> 8, j = idx & 255;
    float4 v;
    if (k == 0) {
      v.x = Wih_d[0 * 256 + j]; v.y = Wih_d[1 * 256 + j];
      v.z = Wih_d[2 * 256 + j]; v.w = Wih_d[3 * 256 + j];
    } else {
      int kk = k - 1;
      v.x = Whh_d[(0 * 256 + j) * 256 + kk];
      v.y = Whh_d[(1 * 256 + j) * 256 + kk];
      v.z = Whh_d[(2 * 256 + j) * 256 + kk];
      v.w = Whh_d[(3 * 256 + j) * 256 + kk];
    }
    reinterpret_cast<float4*>(ws + OFF_WDEC)[idx] = v;
  }
}

// ---------------- attn_in[b][m] = sum_t x[b,t,m]*W_ai[t] + b_ai ----------------
__global__ void k_attn(const float* __restrict__ x, const float* __restrict__ W_ai,
                       const float* __restrict__ b_ai, float* __restrict__ ws) {
  __shared__ float wai[256];
  const int b = blockIdx.x, tid = threadIdx.x;  // 128 threads
  wai[tid] = W_ai[tid];
  wai[128 + tid] = W_ai[128 + tid];
  __syncthreads();
  if (tid < MM) {
    float acc = b_ai[0];
    const float* xp = x + (size_t)b * TT * MM + tid;
    #pragma unroll 8
    for (int t = 0; t < TT; ++t) acc = fmaf(xp[t * MM], wai[t], acc);
    ws[OFF_ATTN + b * MM + tid] = acc;
  }
}

// ---------------- encoder: 1 WG handles 2 batch rows, 256 sequential steps ----------------
__global__ __launch_bounds__(256) void k_encoder(
    const float* __restrict__ x, const float* __restrict__ b_ah,
    const float* __restrict__ W_a, const float* __restrict__ b_a,
    const float* __restrict__ bih_e, const float* __restrict__ bhh_e,
    float* __restrict__ ws) {
  __shared__ float2 hc2[512];     // {b0,b1}: h in [0,256), c in [256,512)
  __shared__ float2 hp2[256];
  __shared__ float wa[256];
  __shared__ float ai[2][81];
  __shared__ float wi[2][81];
  __shared__ float sc[2][96];
  const int tid = threadIdx.x;
  const int b0 = blockIdx.x * 2, b1 = b0 + 1;
  const float* __restrict__ WahT = ws + OFF_WAHT;
  const float4* __restrict__ We4 = reinterpret_cast<const float4*>(ws + OFF_WENC);
  float* __restrict__ enc = ws + OFF_ENC;

  hc2[tid] = make_float2(0.f, 0.f);
  hc2[256 + tid] = make_float2(0.f, 0.f);
  wa[tid] = W_a[tid];
  if (tid < MM) {
    ai[0][tid] = ws[OFF_ATTN + b0 * MM + tid];
    ai[1][tid] = ws[OFF_ATTN + b1 * MM + tid];
  }
  const float bah = b_ah[tid];
  const float bav = b_a[0];
  float4 bias4;
  bias4.x = bih_e[tid] + bhh_e[tid];
  bias4.y = bih_e[256 + tid] + bhh_e[256 + tid];
  bias4.z = bih_e[512 + tid] + bhh_e[512 + tid];
  bias4.w = bih_e[768 + tid] + bhh_e[768 + tid];
  __syncthreads();

  for (int t = 0; t < TT; ++t) {
    // phase 1: hid_proj[j] = [h,c] . W_ah[j,:]
    float a0 = bah, a1 = bah;
    #pragma unroll 8
    for (int k = 0; k < 512; ++k) {
      float w = WahT[k * 256 + tid];
      float2 hv = hc2[k];
      a0 = fmaf(w, hv.x, a0);
      a1 = fmaf(w, hv.y, a1);
    }
    hp2[tid] = make_float2(a0, a1);
    __syncthreads();

    // phase 2: score[m] = sum_t' tanh(hp[t'] + ai[m]) * W_a[t']
    {
      const int sub = tid & 7, mg = tid >> 3;
      #pragma unroll
      for (int mc = 0; mc < 3; ++mc) {
        int m = mc * 32 + mg;
        if (m < MM) {
          float aiv0 = ai[0][m], aiv1 = ai[1][m];
          float e0 = 0.f, e1 = 0.f;
          #pragma unroll 4
          for (int i = 0; i < 32; ++i) {
            int t2 = i * 8 + sub;
            float2 hv = hp2[t2];
            float wv = wa[t2];
            e0 = fmaf(ftanh(hv.x + aiv0), wv, e0);
            e1 = fmaf(ftanh(hv.y + aiv1), wv, e1);
          }
          e0 += __shfl_xor(e0, 1); e0 += __shfl_xor(e0, 2); e0 += __shfl_xor(e0, 4);
          e1 += __shfl_xor(e1, 1); e1 += __shfl_xor(e1, 2); e1 += __shfl_xor(e1, 4);
          if (sub == 0) { sc[0][m] = e0; sc[1][m] = e1; }
        }
      }
    }
    __syncthreads();

    // phase 3: softmax over m, wi = aw * x_t   (wave 0 -> b0, wave 1 -> b1)
    {
      const int wv_id = tid >> 6, lane = tid & 63;
      if (wv_id < 2) {
        float v0 = (lane < 81) ? sc[wv_id][lane] + bav : -1e30f;
        float v1 = (lane < 17) ? sc[wv_id][64 + lane] + bav : -1e30f;
        float mx = fmaxf(v0, v1);
        #pragma unroll
        for (int d = 1; d < 64; d <<= 1) mx = fmaxf(mx, __shfl_xor(mx, d));
        float e0 = (lane < 81) ? __expf(v0 - mx) : 0.f;
        float e1 = (lane < 17) ? __expf(v1 - mx) : 0.f;
        float sm = e0 + e1;
        #pragma unroll
        for (int d = 1; d < 64; d <<= 1) sm += __shfl_xor(sm, d);
        float inv = frcp(sm);
        int bb = (wv_id == 0) ? b0 : b1;
        const float* xr = x + ((size_t)bb * TT + t) * MM;
        if (lane < 81) wi[wv_id][lane] = e0 * inv * xr[lane];
        if (lane < 17) wi[wv_id][64 + lane] = e1 * inv * xr[64 + lane];
      }
    }
    __syncthreads();

    // phase 4: LSTM gates (thread tid owns hidden unit tid across all 4 gates)
    float4 g0 = bias4, g1 = bias4;
    #pragma unroll 4
    for (int k = 0; k < 81; ++k) {
      float4 w = We4[k * 256 + tid];
      float u0 = wi[0][k], u1 = wi[1][k];
      g0.x = fmaf(w.x, u0, g0.x); g0.y = fmaf(w.y, u0, g0.y);
      g0.z = fmaf(w.z, u0, g0.z); g0.w = fmaf(w.w, u0, g0.w);
      g1.x = fmaf(w.x, u1, g1.x); g1.y = fmaf(w.y, u1, g1.y);
      g1.z = fmaf(w.z, u1, g1.z); g1.w = fmaf(w.w, u1, g1.w);
    }
    #pragma unroll 4
    for (int k = 0; k < 256; ++k) {
      float4 w = We4[(81 + k) * 256 + tid];
      float2 hv = hc2[k];
      g0.x = fmaf(w.x, hv.x, g0.x); g0.y = fmaf(w.y, hv.x, g0.y);
      g0.z = fmaf(w.z, hv.x, g0.z); g0.w = fmaf(w.w, hv.x, g0.w);
      g1.x = fmaf(w.x, hv.y, g1.x); g1.y = fmaf(w.y, hv.y, g1.y);
      g1.z = fmaf(w.z, hv.y, g1.z); g1.w = fmaf(w.w, hv.y, g1.w);
    }
    float2 cold = hc2[256 + tid];
    float c0 = fsig(g0.y) * cold.x + fsig(g0.x) * ftanh(g0.z);
    float h0 = fsig(g0.w) * ftanh(c0);
    float c1 = fsig(g1.y) * cold.y + fsig(g1.x) * ftanh(g1.z);
    float h1 = fsig(g1.w) * ftanh(c1);
    __syncthreads();
    hc2[tid] = make_float2(h0, h1);
    hc2[256 + tid] = make_float2(c0, c1);
    enc[((size_t)b0 * TT + t) * HEE + tid] = h0;
    enc[((size_t)b1 * TT + t) * HEE + tid] = h1;
    __syncthreads();
  }
}

// ---------------- encW[b][t] = enc[b,t,:] . W_fc[:256] ----------------
__global__ __launch_bounds__(256) void k_encw(const float* __restrict__ W_fc, float* __restrict__ ws) {
  const float* __restrict__ enc = ws + OFF_ENC;
  const int wv = threadIdx.x >> 6, lane = threadIdx.x & 63;
  float4 wfc = reinterpret_cast<const float4*>(W_fc)[lane];
  for (int r = blockIdx.x * 4 + wv; r < BB * TT; r += 4096) {
    float4 e = reinterpret_cast<const float4*>(enc + (size_t)r * HEE)[lane];
    float d = e.x * wfc.x + e.y * wfc.y + e.z * wfc.z + e.w * wfc.w;
    #pragma unroll
    for (int dd = 1; dd < 64; dd <<= 1) d += __shfl_xor(d, dd);
    if (lane == 0) ws[OFF_ENCW + r] = d;
  }
}

// ---------------- enc_proj^T (bf16): encT[b][h][t] = sum_e enc[b,t,e]*W_d1[h,512+e] ----------------
__global__ __launch_bounds__(256) void k_encproj(const float* __restrict__ W_d1, float* __restrict__ ws) {
  __shared__ float le[16][256];
  const int tid = threadIdx.x;
  const int r0 = blockIdx.x * 16;  // 16 consecutive (b,t) rows, same b
  const float* __restrict__ enc = ws + OFF_ENC;
  __hip_bfloat16* __restrict__ encT = reinterpret_cast<__hip_bfloat16*>(ws + OFF_ENCT);
  #pragma unroll
  for (int rr = 0; rr < 16; ++rr) le[rr][tid] = enc[(size_t)(r0 + rr) * HEE + tid];
  __syncthreads();
  const float* wrow = W_d1 + (size_t)tid * 768 + 512;
  float acc[16];
  #pragma unroll
  for (int rr = 0; rr < 16; ++rr) acc[rr] = 0.f;
  for (int e4 = 0; e4 < 64; ++e4) {
    float4 w = reinterpret_cast<const float4*>(wrow)[e4];
    #pragma unroll
    for (int rr = 0; rr < 16; ++rr) {
      float4 ev = reinterpret_cast<const float4*>(&le[rr][0])[e4];
      acc[rr] += ev.x * w.x + ev.y * w.y + ev.z * w.z + ev.w * w.w;
    }
  }
  const int b = r0 >> 8, t0 = r0 & 255;
  #pragma unroll
  for (int rr = 0; rr < 16; ++rr)
    encT[((size_t)b * 256 + tid) * 256 + (t0 + rr)] = __float2bfloat16(acc[rr]);
}

// ---------------- decoder: 1 WG handles 2 batch rows, 255 sequential steps ----------------
__global__ __launch_bounds__(256) void k_decoder(
    const float* __restrict__ y_history, const float* __restrict__ b_d1,
    const float* __restrict__ W_d2, const float* __restrict__ b_d2,
    const float* __restrict__ W_fc, const float* __restrict__ b_fc,
    const float* __restrict__ bih_d, const float* __restrict__ bhh_d,
    const float* __restrict__ W_ff, const float* __restrict__ b_ff,
    float* __restrict__ ws, float* __restrict__ out) {
  __shared__ float2 hc2[512];
  __shared__ float2 dd2[256];
  __shared__ float wd2s[256];
  __shared__ float2 ew2[256];
  __shared__ float2 scs[256];
  __shared__ float2 awls[256];
  __shared__ float red[4][4];
  const int tid = threadIdx.x;
  const int wv = tid >> 6, lane = tid & 63;
  const int b0 = blockIdx.x * 2, b1 = b0 + 1;
  const float* __restrict__ Wd1hcT = ws + OFF_WD1HC;
  const float4* __restrict__ Wd4 = reinterpret_cast<const float4*>(ws + OFF_WDEC);
  const __hip_bfloat16* __restrict__ encT = reinterpret_cast<const __hip_bfloat16*>(ws + OFF_ENCT);
  const float* __restrict__ enc = ws + OFF_ENC;

  hc2[tid] = make_float2(0.f, 0.f);
  hc2[256 + tid] = make_float2(0.f, 0.f);
  wd2s[tid] = W_d2[tid];
  ew2[tid] = make_float2(ws[OFF_ENCW + b0 * 256 + tid], ws[OFF_ENCW + b1 * 256 + tid]);
  const float bd1 = b_d1[tid];
  const float wfcy = W_fc[256], bfc = b_fc[0];
  float4 biasd;
  biasd.x = bih_d[tid] + bhh_d[tid];
  biasd.y = bih_d[256 + tid] + bhh_d[256 + tid];
  biasd.z = bih_d[512 + tid] + bhh_d[512 + tid];
  biasd.w = bih_d[768 + tid] + bhh_d[768 + tid];
  const float4 wihd = Wd4[tid];  // k==0 row of packed decoder weights
  const __hip_bfloat16* ep0 = encT + (size_t)b0 * 65536 + tid;
  const __hip_bfloat16* ep1 = encT + (size_t)b1 * 65536 + tid;
  __syncthreads();

  for (int s = 0; s < 255; ++s) {
    // phase 1: d = [h,c] . W_d1_hc^T + b_d1
    float a0 = bd1, a1 = bd1;
    #pragma unroll 8
    for (int k = 0; k < 512; ++k) {
      float w = Wd1hcT[k * 256 + tid];
      float2 hv = hc2[k];
      a0 = fmaf(w, hv.x, a0);
      a1 = fmaf(w, hv.y, a1);
    }
    dd2[tid] = make_float2(a0, a1);
    __syncthreads();

    // phase 2: score[t'] = sum_h tanh(enc_proj[t',h] + d[h]) * W_d2[h]   (thread = t')
    float q0 = 0.f, q1 = 0.f;
    #pragma unroll 4
    for (int h = 0; h < 256; ++h) {
      float2 dv = dd2[h];
      float wvv = wd2s[h];
      q0 = fmaf(ftanh(__bfloat162float(ep0[h * 256]) + dv.x), wvv, q0);
      q1 = fmaf(ftanh(__bfloat162float(ep1[h * 256]) + dv.y), wvv, q1);
    }
    scs[tid] = make_float2(q0, q1);
    __syncthreads();

    // phase 3: softmax over t' + y_tild scalar (ctx.W_fc = sum aw*encW)
    float2 v = scs[tid];
    float m0 = v.x, m1 = v.y;
    #pragma unroll
    for (int d = 1; d < 64; d <<= 1) { m0 = fmaxf(m0, __shfl_xor(m0, d)); m1 = fmaxf(m1, __shfl_xor(m1, d)); }
    if (lane == 0) { red[0][wv] = m0; red[1][wv] = m1; }
    __syncthreads();
    m0 = fmaxf(fmaxf(red[0][0], red[0][1]), fmaxf(red[0][2], red[0][3]));
    m1 = fmaxf(fmaxf(red[1][0], red[1][1]), fmaxf(red[1][2], red[1][3]));
    __syncthreads();
    float e0 = __expf(v.x - m0), e1 = __expf(v.y - m1);
    float2 ewv = ew2[tid];
    float den0 = e0, num0 = e0 * ewv.x, den1 = e1, num1 = e1 * ewv.y;
    #pragma unroll
    for (int d = 1; d < 64; d <<= 1) {
      den0 += __shfl_xor(den0, d); num0 += __shfl_xor(num0, d);
      den1 += __shfl_xor(den1, d); num1 += __shfl_xor(num1, d);
    }
    if (lane == 0) { red[0][wv] = den0; red[1][wv] = num0; red[2][wv] = den1; red[3][wv] = num1; }
    __syncthreads();
    den0 = red[0][0] + red[0][1] + red[0][2] + red[0][3];
    num0 = red[1][0] + red[1][1] + red[1][2] + red[1][3];
    den1 = red[2][0] + red[2][1] + red[2][2] + red[2][3];
    num1 = red[3][0] + red[3][1] + red[3][2] + red[3][3];
    const float inv0 = frcp(den0), inv1 = frcp(den1);
    float y0 = num0 * inv0 + y_history[(size_t)b0 * 255 + s] * wfcy + bfc;
    float y1 = num1 * inv1 + y_history[(size_t)b1 * 255 + s] * wfcy + bfc;
    if (s == 254) awls[tid] = make_float2(e0 * inv0, e1 * inv1);
    __syncthreads();

    // phase 5: decoder LSTM
    float4 g0, g1;
    g0.x = fmaf(y0, wihd.x, biasd.x); g0.y = fmaf(y0, wihd.y, biasd.y);
    g0.z = fmaf(y0, wihd.z, biasd.z); g0.w = fmaf(y0, wihd.w, biasd.w);
    g1.x = fmaf(y1, wihd.x, biasd.x); g1.y = fmaf(y1, wihd.y, biasd.y);
    g1.z = fmaf(y1, wihd.z, biasd.z); g1.w = fmaf(y1, wihd.w, biasd.w);
    #pragma unroll 4
    for (int k = 0; k < 256; ++k) {
      float4 w = Wd4[(1 + k) * 256 + tid];
      float2 hv = hc2[k];
      g0.x = fmaf(w.x, hv.x, g0.x); g0.y = fmaf(w.y, hv.x, g0.y);
      g0.z = fmaf(w.z, hv.x, g0.z); g0.w = fmaf(w.w, hv.x, g0.w);
      g1.x = fmaf(w.x, hv.y, g1.x); g1.y = fmaf(w.y, hv.y, g1.y);
      g1.z = fmaf(w.z, hv.y, g1.z); g1.w = fmaf(w.w, hv.y, g1.w);
    }
    float2 cold = hc2[256 + tid];
    float c0 = fsig(g0.y) * cold.x + fsig(g0.x) * ftanh(g0.z);
    float h0 = fsig(g0.w) * ftanh(c0);
    float c1 = fsig(g1.y) * cold.y + fsig(g1.x) * ftanh(g1.z);
    float h1 = fsig(g1.w) * ftanh(c1);
    __syncthreads();
    hc2[tid] = make_float2(h0, h1);
    hc2[256 + tid] = make_float2(c0, c1);
    __syncthreads();
  }

  // final: full ctx (last step's aw) + out = [h_fin, ctx] . W_ff + b_ff
  float ctx0 = 0.f, ctx1 = 0.f;
  #pragma unroll 4
  for (int t2 = 0; t2 < 256; ++t2) {
    float2 awv = awls[t2];
    ctx0 = fmaf(awv.x, enc[((size_t)b0 * TT + t2) * HEE + tid], ctx0);
    ctx1 = fmaf(awv.y, enc[((size_t)b1 * TT + t2) * HEE + tid], ctx1);
  }
  float2 hfin = hc2[tid];
  float p0 = hfin.x * W_ff[tid] + ctx0 * W_ff[256 + tid];
  float p1 = hfin.y * W_ff[tid] + ctx1 * W_ff[256 + tid];
  #pragma unroll
  for (int d = 1; d < 64; d <<= 1) { p0 += __shfl_xor(p0, d); p1 += __shfl_xor(p1, d); }
  if (lane == 0) { red[0][wv] = p0; red[1][wv] = p1; }
  __syncthreads();
  if (tid == 0) {
    out[b0] = red[0][0] + red[0][1] + red[0][2] + red[0][3] + b_ff[0];
    out[b1] = red[1][0] + red[1][1] + red[1][2] + red[1][3] + b_ff[0];
  }
}

extern "C" void kernel_launch(void* const* d_in, const int* in_sizes, int n_in,
                              void* d_out, int out_size, void* d_ws, size_t ws_size,
                              hipStream_t stream) {
  if (ws_size < (size_t)WS_FLOATS * sizeof(float)) return;  // fail loudly (out stays poisoned)
  const float* x     = (const float*)d_in[0];
  const float* y_h   = (const float*)d_in[1];
  const float* W_ah  = (const float*)d_in[2];
  const float* b_ah  = (const float*)d_in[3];
  const float* W_ai  = (const float*)d_in[4];
  const float* b_ai  = (const float*)d_in[5];
  const float* W_a   = (const float*)d_in[6];
  const float* b_a   = (const float*)d_in[7];
  const float* Wih_e = (const float*)d_in[8];
  const float* Whh_e = (const float*)d_in[9];
  const float* bih_e = (const float*)d_in[10];
  const float* bhh_e = (const float*)d_in[11];
  const float* W_d1  = (const float*)d_in[12];
  const float* b_d1  = (const float*)d_in[13];
  const float* W_d2  = (const float*)d_in[14];
  const float* b_d2  = (const float*)d_in[15];
  const float* W_fc  = (const float*)d_in[16];
  const float* b_fc  = (const float*)d_in[17];
  const float* Wih_d = (const float*)d_in[18];
  const float* Whh_d = (const float*)d_in[19];
  const float* bih_d = (const float*)d_in[20];
  const float* bhh_d = (const float*)d_in[21];
  const float* W_ff  = (const float*)d_in[22];
  const float* b_ff  = (const float*)d_in[23];
  float* ws  = (float*)d_ws;
  float* out = (float*)d_out;

  k_prep<<<512, 256, 0, stream>>>(W_ah, Wih_e, Whh_e, W_d1, Wih_d, Whh_d, ws);
  k_attn<<<512, 128, 0, stream>>>(x, W_ai, b_ai, ws);
  k_encoder<<<256, 256, 0, stream>>>(x, b_ah, W_a, b_a, bih_e, bhh_e, ws);
  k_encw<<<1024, 256, 0, stream>>>(W_fc, ws);
  k_encproj<<<8192, 256, 0, stream>>>(W_d1, ws);
  k_decoder<<<256, 256, 0, stream>>>(y_h, b_d1, W_d2, b_d2, W_fc, b_fc,
                                     bih_d, bhh_d, W_ff, b_ff, ws, out);
}